// Round 9
// baseline (357.870 us; speedup 1.0000x reference)
//
#include <hip/hip_runtime.h>
#include <hip/hip_bf16.h>

// GatherModel: 6-step NNConv message passing, reformulated:
//   agg[n,o] = sum_{ki} S[n,ki] * T'[ki,o]   (ki = k*42+i, K padded to 1824)
//   S[n]     = H_n^T @ X_n  (per-node MFMA GEMM over edges)
//   h'[e] = [relu(e_feat@en_w1+b1), 1]       (step-invariant, bf16)
// R9: kill phase-1 latency.
//  - hpT: h' pre-transposed into MFMA-A fragment order per global-aligned
//    32-edge chunk -> A load = 3 coalesced b128 (was 24 tiny loads);
//    node boundaries via zero-masking A (wave-uniform fast path).
//  - out buffers bf16 stride 48: gathers are 2B, no cvt, same MFMA bits.
//  - 8 nodes / 4 waves / 256 thr, LDS 32.4KB -> 5 blocks/CU (20 waves/CU).
//  - both nodes' chunk loads issued before either's MFMAs (2x MLP).
// Fragment conventions identical to R6/R8-validated.

#define N_NODES 10000
#define N_EDGES 160000
#define NCHK 5000      // N_EDGES/32 global-aligned chunks
#define D 42
#define DE 10
#define XSTR 48        // out16 stride (cols 42..47 = 0)
#define KI 1806        // 43*42
#define NKSTEP 57      // K-steps of 32 (K padded to 1824)
#define SSTR 1832      // sS row stride in shorts (916 dw, %32=20 -> 2-way ok)

typedef __attribute__((ext_vector_type(8))) short short8;
typedef __attribute__((ext_vector_type(4))) float f32x4;

__global__ __launch_bounds__(256) void k_lin0(const float* __restrict__ nf,
        const float* __restrict__ w, const float* __restrict__ b,
        __hip_bfloat16* __restrict__ out16) {
    int idx = blockIdx.x * 256 + threadIdx.x;
    if (idx >= N_NODES * XSTR) return;
    int n = idx / XSTR, j = idx % XSTR;
    float v = 0.f;
    if (j < D) {
        const float* row = nf + n * D;
        float acc = b[j];
        #pragma unroll
        for (int i = 0; i < D; ++i) acc = fmaf(row[i], w[i * D + j], acc);
        v = fmaxf(acc, 0.f);
    }
    out16[idx] = __float2bfloat16(v);
}

// B-fragments for phase 2: Bfr[((nt*57+ks)*64+lane)*8+j] = bf16(T'[ki][col]),
// col = nt*16+(lane&15), ki = ks*32+(lane>>4)*8+j. Zero outside range.
__global__ __launch_bounds__(256) void k_T2B(const float* __restrict__ w2,
        const float* __restrict__ b2, __hip_bfloat16* __restrict__ Bfr) {
    int idx = blockIdx.x * 256 + threadIdx.x;
    if (idx >= 3 * NKSTEP * 64 * 8) return;
    int j = idx & 7, lane = (idx >> 3) & 63;
    int ks = (idx >> 9) % NKSTEP, nt = idx / (NKSTEP * 512);
    int col = nt * 16 + (lane & 15);
    int k = ks * 32 + ((lane >> 4) * 8) + j;
    float v = 0.f;
    if (col < D && k < KI) {
        int kk = k / D, ii = k % D;
        v = (kk < D) ? w2[kk * (D * D) + ii * D + col] : b2[ii * D + col];
    }
    Bfr[idx] = __float2bfloat16(v);
}

__global__ __launch_bounds__(256) void k_hist(const int* __restrict__ dst,
        int* __restrict__ cnt) {
    int e = blockIdx.x * 256 + threadIdx.x;
    if (e < N_EDGES) atomicAdd(&cnt[dst[e]], 1);
}

__global__ __launch_bounds__(1024) void k_scan(const int* __restrict__ cnt,
        int* __restrict__ row_ptr, int* __restrict__ cursor) {
    __shared__ int buf[1024];
    __shared__ int s_run;
    const int t = threadIdx.x;
    if (t == 0) s_run = 0;
    __syncthreads();
    for (int base = 0; base < N_NODES; base += 1024) {
        int v = (base + t < N_NODES) ? cnt[base + t] : 0;
        buf[t] = v;
        __syncthreads();
        for (int off = 1; off < 1024; off <<= 1) {
            int add = (t >= off) ? buf[t - off] : 0;
            __syncthreads();
            buf[t] += add;
            __syncthreads();
        }
        int excl = buf[t] - v;
        if (base + t < N_NODES) {
            int val = s_run + excl;
            row_ptr[base + t] = val;
            cursor[base + t]  = val;
        }
        __syncthreads();
        if (t == 0) s_run += buf[1023];
        __syncthreads();
    }
    if (t == 0) { row_ptr[N_NODES] = s_run; cursor[N_NODES] = s_run; }
}

__global__ __launch_bounds__(256) void k_scatter(const int* __restrict__ dst,
        const int* __restrict__ src, int* __restrict__ cursor,
        int* __restrict__ srcp, int* __restrict__ eperm) {
    int e = blockIdx.x * 256 + threadIdx.x;
    if (e < N_EDGES) {
        int p = atomicAdd(&cursor[dst[e]], 1);
        srcp[p] = src[e];
        eperm[p] = e;
    }
}

// hpT[c][k][e'] = bf16(h'[edge at CSR pos c*32+e'][k]), k<42: relu MLP,
// k==42: 1.0 (bias row), 43..47: 0. Coalesced writes (thread = output idx).
__global__ __launch_bounds__(256) void k_hT(const float* __restrict__ ef,
        const float* __restrict__ w1, const float* __restrict__ b1,
        const int* __restrict__ eperm, __hip_bfloat16* __restrict__ hpT) {
    const int c = blockIdx.x;
    const int t = threadIdx.x;
    for (int j = t; j < 48 * 32; j += 256) {
        int k = j >> 5, ep = j & 31;
        int e = eperm[c * 32 + ep];
        float v;
        if (k < D) {
            const float* row = ef + (size_t)e * DE;
            float acc = b1[k];
            #pragma unroll
            for (int i = 0; i < DE; ++i) acc = fmaf(row[i], w1[i * D + k], acc);
            v = fmaxf(acc, 0.f);
        } else {
            v = (k == D) ? 1.0f : 0.f;
        }
        hpT[(size_t)c * 1536 + j] = __float2bfloat16(v);
    }
}

#define MFMA(A, B, C) C = __builtin_amdgcn_mfma_f32_16x16x32_bf16(A, B, C, 0, 0, 0)

// Fused step: 256 threads (4 waves), 8 nodes per block, grid 1250.
__global__ __launch_bounds__(256) void k_step3(
        const __hip_bfloat16* __restrict__ hpT,
        const __hip_bfloat16* __restrict__ out_in,
        const int* __restrict__ srcp, const int* __restrict__ row_ptr,
        const __hip_bfloat16* __restrict__ Bfr,
        const float* __restrict__ nf, const float* __restrict__ msg_w,
        const float* __restrict__ msg_b, const float* __restrict__ conv_b,
        __hip_bfloat16* __restrict__ out16_dst, float* __restrict__ fout,
        int last) {
    __shared__ __align__(16) __hip_bfloat16 sS[8 * SSTR];   // 28.6 KB
    __shared__ float sR[8 * 48];                            // 1.5 KB
    __shared__ float sM[8 * 48];                            // 1.5 KB
    const int t = threadIdx.x;
    const int wv = t >> 6;
    const int l = t & 63;
    const int g = l >> 4;
    const int g8 = g * 8;
    const int cl = l & 15;
    const int n0 = blockIdx.x * 8;
    const short* hpTs = (const short*)hpT;
    const short* xs = (const short*)out_in;

    for (int i = t; i < 8 * 48; i += 256) sR[i] = 0.f;
    for (int i = t; i < 8 * 18; i += 256)                   // zero ki pads
        sS[(i / 18) * SSTR + KI + (i % 18)] = __float2bfloat16(0.f);

    // ---- phase 1: per-node S = h'^T @ X via MFMA, 2 nodes/wave, ----
    // ---- both nodes' loads issued before either's MFMAs          ----
    const int nodeA = n0 + wv * 2, nodeB = nodeA + 1;
    const int begA = row_ptr[nodeA], endA = row_ptr[nodeA + 1];
    const int begB = endA, endB = row_ptr[nodeB + 1];       // CSR contiguity
    const int c0A = begA >> 5, ncA = (endA > begA) ? ((endA - 1) >> 5) - c0A + 1 : 0;
    const int c0B = begB >> 5, ncB = (endB > begB) ? ((endB - 1) >> 5) - c0B + 1 : 0;
    const int ncmax = max(ncA, ncB);

    f32x4 cA[9], cB[9];
    #pragma unroll
    for (int i = 0; i < 9; ++i) { cA[i] = {0.f,0.f,0.f,0.f}; cB[i] = cA[i]; }

    for (int ci = 0; ci < ncmax; ++ci) {
        short8 aA0, aA1, aA2, bA0, bA1, bA2;
        short8 aB0, aB1, aB2, bB0, bB1, bB2;
        bool doA = ci < ncA, doB = ci < ncB;
        if (doA) {          // issue node-A loads
            const int c = c0A + ci, c32 = c << 5;
            const short* hb = hpTs + (size_t)c * 1536 + cl * 32 + g8;
            aA0 = *(const short8*)(hb);
            aA1 = *(const short8*)(hb + 16 * 32);
            aA2 = *(const short8*)(hb + 32 * 32);
            int4 s0 = *(const int4*)(srcp + c32 + g8);
            int4 s1 = *(const int4*)(srcp + c32 + g8 + 4);
            const int se[8] = {s0.x, s0.y, s0.z, s0.w, s1.x, s1.y, s1.z, s1.w};
            #pragma unroll
            for (int j = 0; j < 8; ++j) {
                const short* xr = xs + (size_t)se[j] * XSTR + cl;
                bA0[j] = xr[0]; bA1[j] = xr[16]; bA2[j] = xr[32];
            }
            if (c32 < begA || c32 + 32 > endA) {
                #pragma unroll
                for (int j = 0; j < 8; ++j) {
                    int ep = c32 + g8 + j;
                    if (ep < begA || ep >= endA) { aA0[j] = 0; aA1[j] = 0; aA2[j] = 0; }
                }
            }
        }
        if (doB) {          // issue node-B loads
            const int c = c0B + ci, c32 = c << 5;
            const short* hb = hpTs + (size_t)c * 1536 + cl * 32 + g8;
            aB0 = *(const short8*)(hb);
            aB1 = *(const short8*)(hb + 16 * 32);
            aB2 = *(const short8*)(hb + 32 * 32);
            int4 s0 = *(const int4*)(srcp + c32 + g8);
            int4 s1 = *(const int4*)(srcp + c32 + g8 + 4);
            const int se[8] = {s0.x, s0.y, s0.z, s0.w, s1.x, s1.y, s1.z, s1.w};
            #pragma unroll
            for (int j = 0; j < 8; ++j) {
                const short* xr = xs + (size_t)se[j] * XSTR + cl;
                bB0[j] = xr[0]; bB1[j] = xr[16]; bB2[j] = xr[32];
            }
            if (c32 < begB || c32 + 32 > endB) {
                #pragma unroll
                for (int j = 0; j < 8; ++j) {
                    int ep = c32 + g8 + j;
                    if (ep < begB || ep >= endB) { aB0[j] = 0; aB1[j] = 0; aB2[j] = 0; }
                }
            }
        }
        if (doA) {
            MFMA(aA0, bA0, cA[0]); MFMA(aA0, bA1, cA[1]); MFMA(aA0, bA2, cA[2]);
            MFMA(aA1, bA0, cA[3]); MFMA(aA1, bA1, cA[4]); MFMA(aA1, bA2, cA[5]);
            MFMA(aA2, bA0, cA[6]); MFMA(aA2, bA1, cA[7]); MFMA(aA2, bA2, cA[8]);
        }
        if (doB) {
            MFMA(aB0, bB0, cB[0]); MFMA(aB0, bB1, cB[1]); MFMA(aB0, bB2, cB[2]);
            MFMA(aB1, bB0, cB[3]); MFMA(aB1, bB1, cB[4]); MFMA(aB1, bB2, cB[5]);
            MFMA(aB2, bB0, cB[6]); MFMA(aB2, bB1, cB[7]); MFMA(aB2, bB2, cB[8]);
        }
    }
    // C -> sS[nloc][ki = m*42 + col]; m = k-row (<43), col = i (<42)
    #define ST(CC, NLOC, MT, NT)                                             \
        _Pragma("unroll")                                                    \
        for (int r = 0; r < 4; ++r) {                                        \
            int m = (MT) * 16 + g * 4 + r;                                   \
            int col = (NT) * 16 + cl;                                        \
            if (m < 43 && col < D)                                           \
                sS[(NLOC) * SSTR + m * D + col] = __float2bfloat16(CC[r]);   \
        }
    {
        const int nlA = wv * 2, nlB = nlA + 1;
        ST(cA[0], nlA, 0, 0) ST(cA[1], nlA, 0, 1) ST(cA[2], nlA, 0, 2)
        ST(cA[3], nlA, 1, 0) ST(cA[4], nlA, 1, 1) ST(cA[5], nlA, 1, 2)
        ST(cA[6], nlA, 2, 0) ST(cA[7], nlA, 2, 1) ST(cA[8], nlA, 2, 2)
        ST(cB[0], nlB, 0, 0) ST(cB[1], nlB, 0, 1) ST(cB[2], nlB, 0, 2)
        ST(cB[3], nlB, 1, 0) ST(cB[4], nlB, 1, 1) ST(cB[5], nlB, 1, 2)
        ST(cB[6], nlB, 2, 0) ST(cB[7], nlB, 2, 1) ST(cB[8], nlB, 2, 2)
    }
    #undef ST
    __syncthreads();

    // ---- phase 2: agg = S @ T' (57 K-steps split 15/14/14/14) ----
    {
        const int ks0 = (wv == 0) ? 0 : (wv * 14 + 1);
        const int ks1 = wv * 14 + 15;
        f32x4 d0 = {0.f,0.f,0.f,0.f}, d1 = d0, d2 = d0;
        const short* sSrow = (const short*)sS + (cl & 7) * SSTR + g8;
        const short* bb = (const short*)Bfr + (size_t)l * 8;
        for (int ks = ks0; ks < ks1; ++ks) {
            short8 a  = *(const short8*)(sSrow + ks * 32);
            short8 B0 = *(const short8*)(bb + (size_t)(0 * NKSTEP + ks) * 512);
            short8 B1 = *(const short8*)(bb + (size_t)(1 * NKSTEP + ks) * 512);
            short8 B2 = *(const short8*)(bb + (size_t)(2 * NKSTEP + ks) * 512);
            MFMA(a, B0, d0); MFMA(a, B1, d1); MFMA(a, B2, d2);
        }
        if (g < 2) {                       // rows 0..7 real, 8..15 duplicates
            const int rl = g * 4;
            #pragma unroll
            for (int r = 0; r < 4; ++r) {
                atomicAdd(&sR[(rl + r) * 48 + cl],      d0[r]);
                atomicAdd(&sR[(rl + r) * 48 + 16 + cl], d1[r]);
                atomicAdd(&sR[(rl + r) * 48 + 32 + cl], d2[r]);
            }
        }
    }
    __syncthreads();

    // ---- phase 3: m = relu(agg + out_in + conv_b); stage msg_w -> sW ----
    float* sW = (float*)sS;                      // sS dead after phase 2
    for (int i = t; i < D * D; i += 256) sW[i] = msg_w[i];
    for (int idx = t; idx < 8 * 48; idx += 256) {
        int nl_ = idx / 48, o = idx % 48;
        float mv = 0.f;
        if (o < D) {
            float res = __bfloat162float(out_in[(size_t)(n0 + nl_) * XSTR + o]);
            mv = fmaxf(sR[idx] + res + conv_b[o], 0.f);
        }
        sM[idx] = mv;
    }
    __syncthreads();

    // ---- phase 4: out' = relu(m @ msg_w + msg_b) [+ nf if last] ----
    for (int idx = t; idx < 8 * 48; idx += 256) {
        int nl_ = idx / 48, pcol = idx % 48;
        if (pcol < D) {
            float s = msg_b[pcol];
            #pragma unroll 6
            for (int o = 0; o < D; ++o)
                s = fmaf(sM[nl_ * 48 + o], sW[o * D + pcol], s);
            float v = fmaxf(s, 0.f);
            if (last) {
                fout[(size_t)(n0 + nl_) * D + pcol] =
                    v + nf[(size_t)(n0 + nl_) * D + pcol];
            } else {
                out16_dst[(size_t)(n0 + nl_) * XSTR + pcol] = __float2bfloat16(v);
            }
        } else if (!last) {
            out16_dst[(size_t)(n0 + nl_) * XSTR + pcol] = __float2bfloat16(0.f);
        }
    }
}

extern "C" void kernel_launch(void* const* d_in, const int* in_sizes, int n_in,
                              void* d_out, int out_size, void* d_ws, size_t ws_size,
                              hipStream_t stream) {
    const float* nf    = (const float*)d_in[0];
    const float* ef    = (const float*)d_in[1];
    const int*   src   = (const int*)d_in[2];
    const int*   dst   = (const int*)d_in[3];
    const float* lin0w = (const float*)d_in[4];
    const float* lin0b = (const float*)d_in[5];
    const float* msgw  = (const float*)d_in[6];
    const float* msgb  = (const float*)d_in[7];
    const float* enw1  = (const float*)d_in[8];
    const float* enb1  = (const float*)d_in[9];
    const float* enw2  = (const float*)d_in[10];
    const float* enb2  = (const float*)d_in[11];
    const float* convb = (const float*)d_in[12];

    // ws layout (~20 MB)
    char* p = (char*)d_ws;
    auto alloc = [&](size_t bytes) -> char* {
        char* r = p; p += (bytes + 255) & ~(size_t)255; return r;
    };
    __hip_bfloat16* outA = (__hip_bfloat16*)alloc((size_t)N_NODES * XSTR * 2);
    __hip_bfloat16* outB = (__hip_bfloat16*)alloc((size_t)N_NODES * XSTR * 2);
    __hip_bfloat16* hpT  = (__hip_bfloat16*)alloc((size_t)NCHK * 1536 * 2);
    __hip_bfloat16* Bfr  = (__hip_bfloat16*)alloc((size_t)3 * NKSTEP * 64 * 8 * 2);
    int* cnt    = (int*)alloc((N_NODES + 1) * 4);
    int* rowp   = (int*)alloc((N_NODES + 1) * 4);
    int* cur    = (int*)alloc((N_NODES + 1) * 4);
    int* srcp   = (int*)alloc((size_t)N_EDGES * 4);
    int* eperm  = (int*)alloc((size_t)N_EDGES * 4);

    hipMemsetAsync(cnt, 0, (N_NODES + 1) * 4, stream);
    k_lin0<<<(N_NODES * XSTR + 255) / 256, 256, 0, stream>>>(nf, lin0w, lin0b, outA);
    k_T2B<<<(3 * NKSTEP * 64 * 8 + 255) / 256, 256, 0, stream>>>(enw2, enb2, Bfr);
    k_hist<<<(N_EDGES + 255) / 256, 256, 0, stream>>>(dst, cnt);
    k_scan<<<1, 1024, 0, stream>>>(cnt, rowp, cur);
    k_scatter<<<(N_EDGES + 255) / 256, 256, 0, stream>>>(dst, src, cur, srcp, eperm);
    k_hT<<<NCHK, 256, 0, stream>>>(ef, enw1, enb1, eperm, hpT);

    const int tiles = N_NODES / 8;                // 1250 exactly
    __hip_bfloat16* bufs[2] = {outA, outB};
    for (int s_i = 0; s_i < 6; ++s_i) {
        const __hip_bfloat16* cin = bufs[s_i % 2];
        __hip_bfloat16* cout = bufs[(s_i + 1) % 2];
        int last = (s_i == 5) ? 1 : 0;
        k_step3<<<tiles, 256, 0, stream>>>(hpT, cin, srcp, rowp, Bfr,
                                           nf, msgw, msgb, convb,
                                           cout, (float*)d_out, last);
    }
}